// Round 5
// baseline (240.230 us; speedup 1.0000x reference)
//
#include <hip/hip_runtime.h>
#include <stdint.h>

// ---------------------------------------------------------------------------
// SparseAttention: B=1 S=4096 D=1024 H=16 HD=64, BLOCK=128 C=32
// cvt_x -> tpose4 -> gemm_bt<0>(QKV, q pre-scaled by 0.125*log2e) ->
// attn_kernel (256thr jobs, heavy-first, single drain-barrier pipeline) ->
// gemm_bt<1>. Base-2 softmax. LDS XOR-swizzled on 16B granules.
// ---------------------------------------------------------------------------

#define S_LEN 4096

typedef __bf16 bf16x8 __attribute__((ext_vector_type(8)));
typedef float  f32x4  __attribute__((ext_vector_type(4)));

__device__ __forceinline__ uint16_t f2bf(float f) {
    uint32_t u = __builtin_bit_cast(uint32_t, f);
    u += 0x7fffu + ((u >> 16) & 1u);   // RNE
    return (uint16_t)(u >> 16);
}
__device__ __forceinline__ uint32_t pack2bf(float lo, float hi) {
    return (uint32_t)f2bf(lo) | ((uint32_t)f2bf(hi) << 16);
}
__device__ __forceinline__ void gload_lds16(const uint16_t* g, uint16_t* l) {
    __builtin_amdgcn_global_load_lds(
        (const __attribute__((address_space(1))) void*)g,
        (__attribute__((address_space(3))) void*)l, 16, 0, 0);
}

// gather-key mapping: chunk ch (64 keys), local key kl
__device__ __forceinline__ int key_of(int b, int ngc, int ch, int kl) {
    if (ch >= ngc) return b * 128 + (ch - ngc) * 64 + kl;   // own block
    int t = ch * 64 + kl;                                    // prev-block gather
    int kb = t / 33, rr = t - kb * 33;
    return kb * 128 + (rr == 0 ? 0 : 95 + rr);
}

// ---------------- x fp32 -> bf16 -------------------------------------------
__global__ __launch_bounds__(256) void cvt_x_kernel(const float* __restrict__ x,
                                                    uint16_t* __restrict__ xb) {
    int i = (blockIdx.x * 256 + threadIdx.x) * 4;
    const float4 v = *(const float4*)(x + i);
    ushort4 o;
    o.x = f2bf(v.x); o.y = f2bf(v.y); o.z = f2bf(v.z); o.w = f2bf(v.w);
    *(ushort4*)(xb + i) = o;
}

// ---------------- W [K=1024][N=1024] fp32 -> [N][K] bf16 -------------------
__global__ __launch_bounds__(256) void tpose4(const float* __restrict__ Wq,
                                              const float* __restrict__ Wk,
                                              const float* __restrict__ Wv,
                                              const float* __restrict__ Wo,
                                              uint16_t* __restrict__ wqkvt,
                                              uint16_t* __restrict__ wot) {
    __shared__ float tile[64][65];
    const int z = blockIdx.z;
    const float* src = (z == 0) ? Wq : (z == 1) ? Wk : (z == 2) ? Wv : Wo;
    uint16_t* dst = (z < 3) ? (wqkvt + (size_t)z * 1024 * 1024) : wot;
    const int ro = blockIdx.y * 64, co = blockIdx.x * 64;
    const int c = threadIdx.x & 63, r4 = threadIdx.x >> 6;
#pragma unroll
    for (int i = 0; i < 16; i++) {
        int r = i * 4 + r4;
        tile[r][c] = src[(size_t)(ro + r) * 1024 + co + c];
    }
    __syncthreads();
#pragma unroll
    for (int i = 0; i < 16; i++) {
        int cc = i * 4 + r4;
        dst[(size_t)(co + cc) * 1024 + ro + c] = f2bf(tile[c][cc]);
    }
}

// ---------------- GEMM: C[M][N] = A[M][1024] * Bt[N][1024]^T ---------------
template <int MODE>
__global__ __launch_bounds__(256) void gemm_bt(const uint16_t* __restrict__ A,
                                               const uint16_t* __restrict__ Bt,
                                               const float* __restrict__ bias0,
                                               const float* __restrict__ bias1,
                                               const float* __restrict__ bias2,
                                               uint16_t* __restrict__ Cb,
                                               float* __restrict__ Cf) {
    __shared__ __attribute__((aligned(16))) uint16_t As[128 * 64];
    __shared__ __attribute__((aligned(16))) uint16_t Bs[128 * 64];
    const int tid = threadIdx.x;
    const int wave = tid >> 6, lane = tid & 63;
    const int quad = lane >> 4, l16 = lane & 15;
    const int row0 = blockIdx.y * 128, col0 = blockIdx.x * 128;
    const int wm = (wave >> 1) * 64, wn = (wave & 1) * 64;
    const int srow = lane >> 3, scol = lane & 7;
    const int gcol = (scol ^ srow) * 8;
    const int sw = (l16 & 7);

    f32x4 acc[4][4];
    const f32x4 z4 = {0.f, 0.f, 0.f, 0.f};
#pragma unroll
    for (int i = 0; i < 4; i++)
#pragma unroll
        for (int j = 0; j < 4; j++) acc[i][j] = z4;

    for (int k0 = 0; k0 < 1024; k0 += 64) {
        __syncthreads();
#pragma unroll
        for (int i = 0; i < 4; i++) {
            int u = wave * 4 + i;
            int row = u * 8 + srow;
            gload_lds16(A  + (size_t)(row0 + row) * 1024 + k0 + gcol, As + u * 512);
            gload_lds16(Bt + (size_t)(col0 + row) * 1024 + k0 + gcol, Bs + u * 512);
        }
        __syncthreads();
#pragma unroll
        for (int kk = 0; kk < 2; kk++) {
            bf16x8 af[4], bfr[4];
#pragma unroll
            for (int mt = 0; mt < 4; mt++)
                af[mt] = *(const bf16x8*)(As + (wm + mt * 16 + l16) * 64 + ((kk * 4 + quad) ^ sw) * 8);
#pragma unroll
            for (int nt = 0; nt < 4; nt++)
                bfr[nt] = *(const bf16x8*)(Bs + (wn + nt * 16 + l16) * 64 + ((kk * 4 + quad) ^ sw) * 8);
#pragma unroll
            for (int mt = 0; mt < 4; mt++)
#pragma unroll
                for (int nt = 0; nt < 4; nt++) {
                    if (MODE == 0)   // C^T orientation: reg index = n
                        acc[mt][nt] = __builtin_amdgcn_mfma_f32_16x16x32_bf16(
                            bfr[nt], af[mt], acc[mt][nt], 0, 0, 0);
                    else
                        acc[mt][nt] = __builtin_amdgcn_mfma_f32_16x16x32_bf16(
                            af[mt], bfr[nt], acc[mt][nt], 0, 0, 0);
                }
        }
    }

    if (MODE == 0) {
#pragma unroll
        for (int nt = 0; nt < 4; nt++) {
            int n = col0 + wn + nt * 16 + quad * 4;
            int which = n >> 10, c = n & 1023;
            const float* bp = (which == 0) ? bias0 : (which == 1 ? bias1 : bias2);
            const float4 b4 = *(const float4*)(bp + c);
            // q pre-scaled by 1/sqrt(64) * log2(e) for base-2 softmax
            float scv = (which == 0) ? 0.18033688f : 1.0f;
            uint16_t* op = Cb + (size_t)which * S_LEN * 1024 + c;
#pragma unroll
            for (int mt = 0; mt < 4; mt++) {
                int s = row0 + wm + mt * 16 + l16;
                ushort4 pkv;
                pkv.x = f2bf((acc[mt][nt][0] + b4.x) * scv);
                pkv.y = f2bf((acc[mt][nt][1] + b4.y) * scv);
                pkv.z = f2bf((acc[mt][nt][2] + b4.z) * scv);
                pkv.w = f2bf((acc[mt][nt][3] + b4.w) * scv);
                *(ushort4*)(op + (size_t)s * 1024) = pkv;
            }
        }
    } else {
#pragma unroll
        for (int nt = 0; nt < 4; nt++) {
            int n = col0 + wn + nt * 16 + l16;
            float bi = bias0[n];
#pragma unroll
            for (int mt = 0; mt < 4; mt++) {
                int row = row0 + wm + mt * 16 + quad * 4;
#pragma unroll
                for (int r = 0; r < 4; r++)
                    Cf[(size_t)(row + r) * 1024 + n] = acc[mt][nt][r] + bi;
            }
        }
    }
}

// ---------------- sparse flash attention (v5) ------------------------------
// 512 jobs (heavy-first: b = 31 - job/16, h = job%16), 256 thr = 4 waves,
// each wave owns 32 q. One chunk (64 keys) per iteration, all waves share it.
// Pipeline: Vt-write(ci) | issue V(ci+1),K(ci+1) | QK+softmax(ci) |
// barrier(drain) | PV(ci) | cheap barrier.  LDS 40 KiB -> 4 blocks/CU.
__global__ __launch_bounds__(256, 4) void attn_kernel(const uint16_t* __restrict__ Qg,
                                                      const uint16_t* __restrict__ Kg,
                                                      const uint16_t* __restrict__ Vg,
                                                      uint16_t* __restrict__ Og) {
    __shared__ __attribute__((aligned(16))) uint16_t SM[20480];  // 40 KiB
    uint16_t* Qs = SM;            // [128][64] 16 KiB
    uint16_t* Kb = SM + 8192;     // 2 x [64][64] 16 KiB (double buffer)
    uint16_t* Vt = SM + 16384;    // [hd64][key64] 8 KiB

    const int job = blockIdx.x;
    const int b = 31 - (job >> 4), h = job & 15;
    const int nprev = 33 * b;
    const int ngc = (nprev + 63) >> 6;
    const int ntot = ngc + 2;
    const size_t hoff = (size_t)h * 64;

    const int tid = threadIdx.x;
    const int wave = tid >> 6, lane = tid & 63;
    const int quad = lane >> 4, l16 = lane & 15;
    const int sw = l16 & 7;
    const int gCol = ((lane & 7) ^ (lane >> 3)) * 8;   // swizzled 16B chunk
    const int kp = tid & 31, hseg = tid >> 5;          // V stager coords

    // ---- preload: Q [128][64], K(0), V(0)
#pragma unroll
    for (int i = 0; i < 4; i++) {
        int seg = i * 4 + wave;
        int row = seg * 8 + (lane >> 3);
        gload_lds16(Qg + (size_t)(b * 128 + row) * 1024 + hoff + gCol, Qs + seg * 512);
    }
#pragma unroll
    for (int i = 0; i < 2; i++) {
        int u = i * 4 + wave;
        int row = u * 8 + (lane >> 3);
        int key = key_of(b, ngc, 0, row);
        gload_lds16(Kg + (size_t)key * 1024 + hoff + gCol, Kb + u * 512);
    }
    uint4 va4, vc4;
    {
        int vk0 = key_of(b, ngc, 0, 2 * kp);
        int vk1 = key_of(b, ngc, 0, 2 * kp + 1);
        va4 = *(const uint4*)(Vg + (size_t)vk0 * 1024 + hoff + hseg * 8);
        vc4 = *(const uint4*)(Vg + (size_t)vk1 * 1024 + hoff + hseg * 8);
    }
    __syncthreads();

    float m_run[2] = {-3e38f, -3e38f}, l_run[2] = {0.f, 0.f};
    f32x4 o[4][2];
    const f32x4 z4 = {0.f, 0.f, 0.f, 0.f};
#pragma unroll
    for (int mt = 0; mt < 4; mt++) { o[mt][0] = z4; o[mt][1] = z4; }

    int cur = 0;
    for (int ci = 0; ci < ntot; ci++) {
        // (1) V^T write for chunk ci from regs (b32 interleaved, conflict-free)
        {
            uint32_t av[4] = {va4.x, va4.y, va4.z, va4.w};
            uint32_t cv[4] = {vc4.x, vc4.y, vc4.z, vc4.w};
#pragma unroll
            for (int j = 0; j < 4; j++) {
                uint32_t lo = (av[j] & 0xffffu) | (cv[j] << 16);
                uint32_t hi = (av[j] >> 16) | (cv[j] & 0xffff0000u);
                int hd0 = hseg * 8 + 2 * j, hd1 = hd0 + 1;
                *(uint32_t*)(Vt + hd0 * 64 + (((kp >> 2) ^ (hd0 & 7)) * 8) + (kp & 3) * 2) = lo;
                *(uint32_t*)(Vt + hd1 * 64 + (((kp >> 2) ^ (hd1 & 7)) * 8) + (kp & 3) * 2) = hi;
            }
        }
        // (2) issue V(ci+1) gather -> regs
        if (ci + 1 < ntot) {
            int vk0 = key_of(b, ngc, ci + 1, 2 * kp);
            int vk1 = key_of(b, ngc, ci + 1, 2 * kp + 1);
            va4 = *(const uint4*)(Vg + (size_t)vk0 * 1024 + hoff + hseg * 8);
            vc4 = *(const uint4*)(Vg + (size_t)vk1 * 1024 + hoff + hseg * 8);
        }
        // (3) issue K(ci+1) DMA -> other buffer
        if (ci + 1 < ntot) {
#pragma unroll
            for (int i = 0; i < 2; i++) {
                int u = i * 4 + wave;
                int row = u * 8 + (lane >> 3);
                int key = key_of(b, ngc, ci + 1, row);
                gload_lds16(Kg + (size_t)key * 1024 + hoff + gCol,
                            Kb + (cur ^ 1) * 4096 + u * 512);
            }
        }

        // (4) S^T = K.Q^T (C: col=q=l16, row=key) + softmax
        const uint16_t* Kc = Kb + cur * 4096;
        f32x4 s[4][2];
#pragma unroll
        for (int kt = 0; kt < 4; kt++) { s[kt][0] = z4; s[kt][1] = z4; }
#pragma unroll
        for (int kk = 0; kk < 2; kk++) {
            bf16x8 ka[4], qb[2];
#pragma unroll
            for (int kt = 0; kt < 4; kt++)
                ka[kt] = *(const bf16x8*)(Kc + (kt * 16 + l16) * 64 + ((kk * 4 + quad) ^ sw) * 8);
#pragma unroll
            for (int qt = 0; qt < 2; qt++)
                qb[qt] = *(const bf16x8*)(Qs + (wave * 32 + qt * 16 + l16) * 64 + ((kk * 4 + quad) ^ sw) * 8);
#pragma unroll
            for (int kt = 0; kt < 4; kt++)
#pragma unroll
                for (int qt = 0; qt < 2; qt++)
                    s[kt][qt] = __builtin_amdgcn_mfma_f32_16x16x32_bf16(
                        ka[kt], qb[qt], s[kt][qt], 0, 0, 0);
        }

        // masking
        if (ci >= ngc) {
            int cb = ci - ngc;
#pragma unroll
            for (int kt = 0; kt < 4; kt++) {
                int keyl = cb * 64 + kt * 16 + quad * 4;
#pragma unroll
                for (int qt = 0; qt < 2; qt++) {
                    int ql = wave * 32 + qt * 16 + l16;
#pragma unroll
                    for (int r = 0; r < 4; r++)
                        if (keyl + r > ql) s[kt][qt][r] = -1e30f;
                }
            }
        } else if (ci == ngc - 1) {
#pragma unroll
            for (int kt = 0; kt < 4; kt++) {
                int tg = ci * 64 + kt * 16 + quad * 4;
#pragma unroll
                for (int r = 0; r < 4; r++)
                    if (tg + r >= nprev) { s[kt][0][r] = -1e30f; s[kt][1][r] = -1e30f; }
            }
        }

        // online softmax (base 2), pack P
        uint32_t pk[4][2][2];
        float al[2];
#pragma unroll
        for (int qt = 0; qt < 2; qt++) {
            float mx = -3e38f;
#pragma unroll
            for (int kt = 0; kt < 4; kt++)
#pragma unroll
                for (int r = 0; r < 4; r++) mx = fmaxf(mx, s[kt][qt][r]);
            mx = fmaxf(mx, __shfl_xor(mx, 16));
            mx = fmaxf(mx, __shfl_xor(mx, 32));
            float mn = fmaxf(m_run[qt], mx);
            float sub = fmaxf(mn, -1e20f);   // guard
            al[qt] = exp2f(m_run[qt] - sub);
            m_run[qt] = mn;
            float ps = 0.f;
#pragma unroll
            for (int kt = 0; kt < 4; kt++) {
                float p0 = exp2f(s[kt][qt][0] - sub);
                float p1 = exp2f(s[kt][qt][1] - sub);
                float p2 = exp2f(s[kt][qt][2] - sub);
                float p3 = exp2f(s[kt][qt][3] - sub);
                ps += (p0 + p1) + (p2 + p3);
                pk[kt][qt][0] = pack2bf(p0, p1);
                pk[kt][qt][1] = pack2bf(p2, p3);
            }
            ps += __shfl_xor(ps, 16);
            ps += __shfl_xor(ps, 32);
            l_run[qt] = l_run[qt] * al[qt] + ps;
        }
        // rescale O
#pragma unroll
        for (int mt = 0; mt < 4; mt++)
#pragma unroll
            for (int qt = 0; qt < 2; qt++)
#pragma unroll
                for (int r = 0; r < 4; r++) o[mt][qt][r] *= al[qt];

        __syncthreads();   // (5) THE drain: V(ci+1)/K(ci+1) had step-4 of slack;
                           //     Vt(ci) now visible to all waves

        // (6) O^T += V^T . P^T (P B-frags via quad shuffles)
        {
            const int srcA = l16 + 32 * (quad & 1);
            const bool hi = (quad >> 1) != 0;
#pragma unroll
            for (int kk = 0; kk < 2; kk++) {
                bf16x8 vaf[4];
#pragma unroll
                for (int mt = 0; mt < 4; mt++)
                    vaf[mt] = *(const bf16x8*)(Vt + (mt * 16 + l16) * 64 + ((kk * 4 + quad) ^ sw) * 8);
#pragma unroll
                for (int qt = 0; qt < 2; qt++) {
                    uint32_t u0a = (uint32_t)__shfl((int)pk[2 * kk][qt][0], srcA);
                    uint32_t u0b = (uint32_t)__shfl((int)pk[2 * kk + 1][qt][0], srcA);
                    uint32_t u1a = (uint32_t)__shfl((int)pk[2 * kk][qt][1], srcA);
                    uint32_t u1b = (uint32_t)__shfl((int)pk[2 * kk + 1][qt][1], srcA);
                    uint32_t u2a = (uint32_t)__shfl((int)pk[2 * kk][qt][0], srcA + 16);
                    uint32_t u2b = (uint32_t)__shfl((int)pk[2 * kk + 1][qt][0], srcA + 16);
                    uint32_t u3a = (uint32_t)__shfl((int)pk[2 * kk][qt][1], srcA + 16);
                    uint32_t u3b = (uint32_t)__shfl((int)pk[2 * kk + 1][qt][1], srcA + 16);
                    uint4 fr;
                    fr.x = hi ? u0b : u0a;
                    fr.y = hi ? u1b : u1a;
                    fr.z = hi ? u2b : u2a;
                    fr.w = hi ? u3b : u3a;
                    bf16x8 pb = __builtin_bit_cast(bf16x8, fr);
#pragma unroll
                    for (int mt = 0; mt < 4; mt++)
                        o[mt][qt] = __builtin_amdgcn_mfma_f32_16x16x32_bf16(
                            vaf[mt], pb, o[mt][qt], 0, 0, 0);
                }
            }
        }
        __syncthreads();   // (7) cheap: nothing in flight; protects Vt & Kb reuse
        cur ^= 1;
    }

    // ---- normalize + store ctx ----
#pragma unroll
    for (int qt = 0; qt < 2; qt++) {
        float inv = 1.0f / l_run[qt];
        int q = b * 128 + wave * 32 + qt * 16 + l16;
#pragma unroll
        for (int mt = 0; mt < 4; mt++) {
            ushort4 pko;
            pko.x = f2bf(o[mt][qt][0] * inv);
            pko.y = f2bf(o[mt][qt][1] * inv);
            pko.z = f2bf(o[mt][qt][2] * inv);
            pko.w = f2bf(o[mt][qt][3] * inv);
            *(ushort4*)(Og + (size_t)q * 1024 + hoff + mt * 16 + quad * 4) = pko;
        }
    }
}

// ---------------------------------------------------------------------------
extern "C" void kernel_launch(void* const* d_in, const int* in_sizes, int n_in,
                              void* d_out, int out_size, void* d_ws, size_t ws_size,
                              hipStream_t stream) {
    const float* x  = (const float*)d_in[0];
    const float* Wq = (const float*)d_in[1];
    const float* bq = (const float*)d_in[2];
    const float* Wk = (const float*)d_in[3];
    const float* bk = (const float*)d_in[4];
    const float* Wv = (const float*)d_in[5];
    const float* bv = (const float*)d_in[6];
    const float* Wo = (const float*)d_in[7];
    const float* bo = (const float*)d_in[8];
    float* out = (float*)d_out;

    uint8_t* ws = (uint8_t*)d_ws;
    uint16_t* x_bf  = (uint16_t*)(ws);                       // 8 MiB
    uint16_t* wqkvt = (uint16_t*)(ws + (8u << 20));          // 6 MiB  [3072][1024]
    uint16_t* wot   = (uint16_t*)(ws + (14u << 20));         // 2 MiB  [1024][1024]
    uint16_t* q_bf  = (uint16_t*)(ws + (16u << 20));         // 8 MiB
    uint16_t* k_bf  = (uint16_t*)(ws + (24u << 20));
    uint16_t* v_bf  = (uint16_t*)(ws + (32u << 20));
    uint16_t* ctx   = (uint16_t*)(ws + (40u << 20));         // 8 MiB
    if (ws_size < (48u << 20)) return;

    cvt_x_kernel<<<4096, 256, 0, stream>>>(x, x_bf);
    tpose4<<<dim3(16, 16, 4), 256, 0, stream>>>(Wq, Wk, Wv, Wo, wqkvt, wot);
    gemm_bt<0><<<dim3(24, 32), 256, 0, stream>>>(x_bf, wqkvt, bq, bk, bv,
                                                 q_bf, nullptr);
    attn_kernel<<<dim3(512), 256, 0, stream>>>(q_bf, k_bf, v_bf, ctx);
    gemm_bt<1><<<dim3(8, 32), 256, 0, stream>>>(ctx, wot, bo, nullptr, nullptr,
                                                nullptr, out);
}

// Round 6
// 189.785 us; speedup vs baseline: 1.2658x; 1.2658x over previous
//
#include <hip/hip_runtime.h>
#include <stdint.h>

// ---------------------------------------------------------------------------
// SparseAttention: B=1 S=4096 D=1024 H=16 HD=64, BLOCK=128 C=32
// cvt_x -> tpose4 -> gemm_bt<0>(QKV, q pre-scaled 0.125*log2e) -> build_vt
// (gathered K copy + pre-transposed/swizzled V tiles) -> attn_kernel (1024
// jobs = (b,h,qhalf), coalesced DMA, ONE barrier/chunk) -> gemm_bt<1>.
// Base-2 softmax. LDS XOR-swizzle: granule g of row r stored at g^(r&7).
// ---------------------------------------------------------------------------

#define S_LEN 4096

typedef __bf16 bf16x8 __attribute__((ext_vector_type(8)));
typedef float  f32x4  __attribute__((ext_vector_type(4)));

__device__ __forceinline__ uint16_t f2bf(float f) {
    uint32_t u = __builtin_bit_cast(uint32_t, f);
    u += 0x7fffu + ((u >> 16) & 1u);   // RNE
    return (uint16_t)(u >> 16);
}
__device__ __forceinline__ uint32_t pack2bf(float lo, float hi) {
    return (uint32_t)f2bf(lo) | ((uint32_t)f2bf(hi) << 16);
}
__device__ __forceinline__ void gload_lds16(const uint16_t* g, uint16_t* l) {
    __builtin_amdgcn_global_load_lds(
        (const __attribute__((address_space(1))) void*)g,
        (__attribute__((address_space(3))) void*)l, 16, 0, 0);
}

// ---------------- x fp32 -> bf16 -------------------------------------------
__global__ __launch_bounds__(256) void cvt_x_kernel(const float* __restrict__ x,
                                                    uint16_t* __restrict__ xb) {
    int i = (blockIdx.x * 256 + threadIdx.x) * 4;
    const float4 v = *(const float4*)(x + i);
    ushort4 o;
    o.x = f2bf(v.x); o.y = f2bf(v.y); o.z = f2bf(v.z); o.w = f2bf(v.w);
    *(ushort4*)(xb + i) = o;
}

// ---------------- W [K=1024][N=1024] fp32 -> [N][K] bf16 -------------------
__global__ __launch_bounds__(256) void tpose4(const float* __restrict__ Wq,
                                              const float* __restrict__ Wk,
                                              const float* __restrict__ Wv,
                                              const float* __restrict__ Wo,
                                              uint16_t* __restrict__ wqkvt,
                                              uint16_t* __restrict__ wot) {
    __shared__ float tile[64][65];
    const int z = blockIdx.z;
    const float* src = (z == 0) ? Wq : (z == 1) ? Wk : (z == 2) ? Wv : Wo;
    uint16_t* dst = (z < 3) ? (wqkvt + (size_t)z * 1024 * 1024) : wot;
    const int ro = blockIdx.y * 64, co = blockIdx.x * 64;
    const int c = threadIdx.x & 63, r4 = threadIdx.x >> 6;
#pragma unroll
    for (int i = 0; i < 16; i++) {
        int r = i * 4 + r4;
        tile[r][c] = src[(size_t)(ro + r) * 1024 + co + c];
    }
    __syncthreads();
#pragma unroll
    for (int i = 0; i < 16; i++) {
        int cc = i * 4 + r4;
        dst[(size_t)(co + cc) * 1024 + ro + c] = f2bf(tile[c][cc]);
    }
}

// ---------------- GEMM: C[M][N] = A[M][1024] * Bt[N][1024]^T ---------------
template <int MODE>
__global__ __launch_bounds__(256) void gemm_bt(const uint16_t* __restrict__ A,
                                               const uint16_t* __restrict__ Bt,
                                               const float* __restrict__ bias0,
                                               const float* __restrict__ bias1,
                                               const float* __restrict__ bias2,
                                               uint16_t* __restrict__ Cb,
                                               float* __restrict__ Cf) {
    __shared__ __attribute__((aligned(16))) uint16_t As[128 * 64];
    __shared__ __attribute__((aligned(16))) uint16_t Bs[128 * 64];
    const int tid = threadIdx.x;
    const int wave = tid >> 6, lane = tid & 63;
    const int quad = lane >> 4, l16 = lane & 15;
    const int row0 = blockIdx.y * 128, col0 = blockIdx.x * 128;
    const int wm = (wave >> 1) * 64, wn = (wave & 1) * 64;
    const int srow = lane >> 3, scol = lane & 7;
    const int gcol = (scol ^ srow) * 8;
    const int sw = (l16 & 7);

    f32x4 acc[4][4];
    const f32x4 z4 = {0.f, 0.f, 0.f, 0.f};
#pragma unroll
    for (int i = 0; i < 4; i++)
#pragma unroll
        for (int j = 0; j < 4; j++) acc[i][j] = z4;

    for (int k0 = 0; k0 < 1024; k0 += 64) {
        __syncthreads();
#pragma unroll
        for (int i = 0; i < 4; i++) {
            int u = wave * 4 + i;
            int row = u * 8 + srow;
            gload_lds16(A  + (size_t)(row0 + row) * 1024 + k0 + gcol, As + u * 512);
            gload_lds16(Bt + (size_t)(col0 + row) * 1024 + k0 + gcol, Bs + u * 512);
        }
        __syncthreads();
#pragma unroll
        for (int kk = 0; kk < 2; kk++) {
            bf16x8 af[4], bfr[4];
#pragma unroll
            for (int mt = 0; mt < 4; mt++)
                af[mt] = *(const bf16x8*)(As + (wm + mt * 16 + l16) * 64 + ((kk * 4 + quad) ^ sw) * 8);
#pragma unroll
            for (int nt = 0; nt < 4; nt++)
                bfr[nt] = *(const bf16x8*)(Bs + (wn + nt * 16 + l16) * 64 + ((kk * 4 + quad) ^ sw) * 8);
#pragma unroll
            for (int mt = 0; mt < 4; mt++)
#pragma unroll
                for (int nt = 0; nt < 4; nt++) {
                    if (MODE == 0)   // C^T orientation: reg index = n
                        acc[mt][nt] = __builtin_amdgcn_mfma_f32_16x16x32_bf16(
                            bfr[nt], af[mt], acc[mt][nt], 0, 0, 0);
                    else
                        acc[mt][nt] = __builtin_amdgcn_mfma_f32_16x16x32_bf16(
                            af[mt], bfr[nt], acc[mt][nt], 0, 0, 0);
                }
        }
    }

    if (MODE == 0) {
#pragma unroll
        for (int nt = 0; nt < 4; nt++) {
            int n = col0 + wn + nt * 16 + quad * 4;
            int which = n >> 10, c = n & 1023;
            const float* bp = (which == 0) ? bias0 : (which == 1 ? bias1 : bias2);
            const float4 b4 = *(const float4*)(bp + c);
            // q pre-scaled by 1/sqrt(64) * log2(e) for base-2 softmax
            float scv = (which == 0) ? 0.18033688f : 1.0f;
            uint16_t* op = Cb + (size_t)which * S_LEN * 1024 + c;
#pragma unroll
            for (int mt = 0; mt < 4; mt++) {
                int s = row0 + wm + mt * 16 + l16;
                ushort4 pkv;
                pkv.x = f2bf((acc[mt][nt][0] + b4.x) * scv);
                pkv.y = f2bf((acc[mt][nt][1] + b4.y) * scv);
                pkv.z = f2bf((acc[mt][nt][2] + b4.z) * scv);
                pkv.w = f2bf((acc[mt][nt][3] + b4.w) * scv);
                *(ushort4*)(op + (size_t)s * 1024) = pkv;
            }
        }
    } else {
#pragma unroll
        for (int nt = 0; nt < 4; nt++) {
            int n = col0 + wn + nt * 16 + l16;
            float bi = bias0[n];
#pragma unroll
            for (int mt = 0; mt < 4; mt++) {
                int row = row0 + wm + mt * 16 + quad * 4;
#pragma unroll
                for (int r = 0; r < 4; r++)
                    Cf[(size_t)(row + r) * 1024 + n] = acc[mt][nt][r] + bi;
            }
        }
    }
}

// ---------------- build gathered K + transposed V tiles --------------------
// grid (80,16): c<64 -> own chunk (keys 64c..64c+63); c>=64 -> gather chunk
// g=c-64 (t = 64g..64g+63, key=key_of(t)). Writes:
//   Vt_all[h][c][hd64][key64], key-granule g stored at g^(hd&7) (pre-swizzle)
//   Kg2[h][t][64] (c>=64 only)  — plain gathered copy.
__global__ __launch_bounds__(256) void build_vt(const uint16_t* __restrict__ Kbf,
                                                const uint16_t* __restrict__ Vbf,
                                                uint16_t* __restrict__ Vt_all,
                                                uint16_t* __restrict__ Kg2) {
    __shared__ uint16_t T[64 * 66];
    const int c = blockIdx.x, h = blockIdx.y;
    const int tid = threadIdx.x;
#pragma unroll
    for (int i = 0; i < 2; i++) {
        int idx = i * 256 + tid;
        int kl = idx >> 3, c8 = idx & 7;
        int key;
        if (c < 64) key = c * 64 + kl;
        else { int t = (c - 64) * 64 + kl; int kb = t / 33, rr = t - kb * 33;
               key = kb * 128 + (rr == 0 ? 0 : 95 + rr); }
        uint4 v = *(const uint4*)(Vbf + (size_t)key * 1024 + h * 64 + c8 * 8);
        uint32_t* tp = (uint32_t*)(T + kl * 66 + c8 * 8);
        tp[0] = v.x; tp[1] = v.y; tp[2] = v.z; tp[3] = v.w;
        if (c >= 64) {
            int t = (c - 64) * 64 + kl;
            uint4 kv = *(const uint4*)(Kbf + (size_t)key * 1024 + h * 64 + c8 * 8);
            *(uint4*)(Kg2 + ((size_t)h * 1024 + t) * 64 + c8 * 8) = kv;
        }
    }
    __syncthreads();
#pragma unroll
    for (int i = 0; i < 2; i++) {
        int idx = i * 256 + tid;
        int hd = idx >> 3, kg8 = idx & 7;
        uint32_t w[4];
#pragma unroll
        for (int p = 0; p < 4; p++) {
            uint16_t lo = T[(kg8 * 8 + 2 * p) * 66 + hd];
            uint16_t hi = T[(kg8 * 8 + 2 * p + 1) * 66 + hd];
            w[p] = (uint32_t)lo | ((uint32_t)hi << 16);
        }
        uint4 o4 = {w[0], w[1], w[2], w[3]};
        *(uint4*)(Vt_all + ((size_t)(h * 80 + c) * 64 + hd) * 64 + ((kg8 ^ (hd & 7)) * 8)) = o4;
    }
}

// ---------------- sparse flash attention (v6) ------------------------------
// 1024 jobs heavy-first: b=31-(job>>5), h=(job&31)>>1, qh=job&1 (64 q each).
// 256 thr = 4 waves x 16 q. All K/Vt staging is contiguous coalesced DMA
// (gather precomputed). ONE __syncthreads per chunk; K+Vt double-buffered.
__global__ __launch_bounds__(256, 4) void attn_kernel(const uint16_t* __restrict__ Qg,
                                                      const uint16_t* __restrict__ Kbf,
                                                      const uint16_t* __restrict__ Kg2,
                                                      const uint16_t* __restrict__ Vt_all,
                                                      uint16_t* __restrict__ Og) {
    __shared__ __attribute__((aligned(16))) uint16_t SM[16384];  // 32 KiB
    // Kbuf(cur)  = SM + cur*4096        (8 KiB each)
    // Vtbuf(cur) = SM + 8192 + cur*4096 (8 KiB each); Q staged at SM+8192 pre-loop

    const int job = blockIdx.x;
    const int b = 31 - (job >> 5);
    const int h = (job & 31) >> 1, qh = job & 1;
    const int nprev = 33 * b;
    const int ngc = (nprev + 63) >> 6;
    const int ntot = ngc + 1 + qh;          // qh=0 skips own chunk 1 (fully masked)
    const size_t hoff = (size_t)h * 64;

    const int tid = threadIdx.x;
    const int wave = tid >> 6, lane = tid & 63;
    const int quad = lane >> 4, l16 = lane & 15;
    const int sw = l16 & 7;

    // ---- stage Q half-tile [64][64] into SM+8192, hoist frags to regs
#pragma unroll
    for (int i = 0; i < 2; i++) {
        int idx = i * 256 + tid;
        int row = idx >> 3, c8 = idx & 7;
        gload_lds16(Qg + (size_t)(b * 128 + qh * 64 + row) * 1024 + hoff + ((c8 ^ (row & 7)) * 8),
                    SM + 8192 + idx * 8);
    }
    __syncthreads();
    bf16x8 qb[2];
#pragma unroll
    for (int kk = 0; kk < 2; kk++)
        qb[kk] = *(const bf16x8*)(SM + 8192 + (wave * 16 + l16) * 64 + (((kk * 4 + quad) ^ sw) * 8));
    __syncthreads();   // everyone has Q frags before DMA overwrites the region

    // ---- DMA chunk 0 into buf 0
    auto stage = [&](int ci, int buf) {
        int vchunk = (ci < ngc) ? (64 + ci) : (2 * b + (ci - ngc));
        const uint16_t* vsrc = Vt_all + ((size_t)(h * 80 + vchunk) * 64) * 64;
#pragma unroll
        for (int i = 0; i < 2; i++) {
            int idx = i * 256 + tid;
            int row = idx >> 3, c8 = idx & 7;
            const uint16_t* kp;
            if (ci < ngc)
                kp = Kg2 + ((size_t)h * 1024 + ci * 64 + row) * 64 + ((c8 ^ (row & 7)) * 8);
            else
                kp = Kbf + (size_t)(b * 128 + (ci - ngc) * 64 + row) * 1024 + hoff + ((c8 ^ (row & 7)) * 8);
            gload_lds16(kp, SM + buf * 4096 + idx * 8);
            gload_lds16(vsrc + idx * 8, SM + 8192 + buf * 4096 + idx * 8);
        }
    };
    stage(0, 0);

    float m_run = -3e38f, l_run = 0.f;
    f32x4 o[4];
    const f32x4 z4 = {0.f, 0.f, 0.f, 0.f};
#pragma unroll
    for (int mt = 0; mt < 4; mt++) o[mt] = z4;

    const int ql = qh * 64 + wave * 16 + l16;   // local q for masking
    const int srcA = l16 + 32 * (quad & 1);
    const bool hi = (quad >> 1) != 0;

    int cur = 0;
    for (int ci = 0; ci < ntot; ci++) {
        __syncthreads();   // drains own DMA(ci) (full prior-iter slack); all
                           // waves done reading buf(ci-1) before we overwrite it
        if (ci + 1 < ntot) stage(ci + 1, cur ^ 1);

        const uint16_t* Kc = SM + cur * 4096;
        const uint16_t* Vc = SM + 8192 + cur * 4096;

        // S^T = K.Q^T  (C: col=q=l16, row=key)
        f32x4 s[4];
#pragma unroll
        for (int kt = 0; kt < 4; kt++) s[kt] = z4;
#pragma unroll
        for (int kk = 0; kk < 2; kk++) {
            bf16x8 ka[4];
#pragma unroll
            for (int kt = 0; kt < 4; kt++)
                ka[kt] = *(const bf16x8*)(Kc + (kt * 16 + l16) * 64 + (((kk * 4 + quad) ^ sw) * 8));
#pragma unroll
            for (int kt = 0; kt < 4; kt++)
                s[kt] = __builtin_amdgcn_mfma_f32_16x16x32_bf16(ka[kt], qb[kk], s[kt], 0, 0, 0);
        }

        // masking
        if (ci >= ngc) {
            int cb = ci - ngc;
#pragma unroll
            for (int kt = 0; kt < 4; kt++) {
                int keyl = cb * 64 + kt * 16 + quad * 4;
#pragma unroll
                for (int r = 0; r < 4; r++)
                    if (keyl + r > ql) s[kt][r] = -1e30f;
            }
        } else if (ci == ngc - 1) {
#pragma unroll
            for (int kt = 0; kt < 4; kt++) {
                int tg = ci * 64 + kt * 16 + quad * 4;
#pragma unroll
                for (int r = 0; r < 4; r++)
                    if (tg + r >= nprev) s[kt][r] = -1e30f;
            }
        }

        // online softmax (base 2) + pack P
        uint32_t pk[4][2];
        float al;
        {
            float mx = -3e38f;
#pragma unroll
            for (int kt = 0; kt < 4; kt++)
#pragma unroll
                for (int r = 0; r < 4; r++) mx = fmaxf(mx, s[kt][r]);
            mx = fmaxf(mx, __shfl_xor(mx, 16));
            mx = fmaxf(mx, __shfl_xor(mx, 32));
            float mn = fmaxf(m_run, mx);
            float sub = fmaxf(mn, -1e20f);
            al = exp2f(m_run - sub);
            m_run = mn;
            float ps = 0.f;
#pragma unroll
            for (int kt = 0; kt < 4; kt++) {
                float p0 = exp2f(s[kt][0] - sub);
                float p1 = exp2f(s[kt][1] - sub);
                float p2 = exp2f(s[kt][2] - sub);
                float p3 = exp2f(s[kt][3] - sub);
                ps += (p0 + p1) + (p2 + p3);
                pk[kt][0] = pack2bf(p0, p1);
                pk[kt][1] = pack2bf(p2, p3);
            }
            ps += __shfl_xor(ps, 16);
            ps += __shfl_xor(ps, 32);
            l_run = l_run * al + ps;
        }
#pragma unroll
        for (int mt = 0; mt < 4; mt++)
#pragma unroll
            for (int r = 0; r < 4; r++) o[mt][r] *= al;

        // O^T += V^T . P^T  (Vt pre-transposed in LDS; P frag via shuffles)
#pragma unroll
        for (int kk = 0; kk < 2; kk++) {
            bf16x8 vaf[4];
#pragma unroll
            for (int mt = 0; mt < 4; mt++)
                vaf[mt] = *(const bf16x8*)(Vc + (mt * 16 + l16) * 64 + (((kk * 4 + quad) ^ sw) * 8));
            uint32_t u0a = (uint32_t)__shfl((int)pk[2 * kk][0], srcA);
            uint32_t u0b = (uint32_t)__shfl((int)pk[2 * kk + 1][0], srcA);
            uint32_t u1a = (uint32_t)__shfl((int)pk[2 * kk][1], srcA);
            uint32_t u1b = (uint32_t)__shfl((int)pk[2 * kk + 1][1], srcA);
            uint32_t u2a = (uint32_t)__shfl((int)pk[2 * kk][0], srcA + 16);
            uint32_t u2b = (uint32_t)__shfl((int)pk[2 * kk + 1][0], srcA + 16);
            uint32_t u3a = (uint32_t)__shfl((int)pk[2 * kk][1], srcA + 16);
            uint32_t u3b = (uint32_t)__shfl((int)pk[2 * kk + 1][1], srcA + 16);
            uint4 fr;
            fr.x = hi ? u0b : u0a;
            fr.y = hi ? u1b : u1a;
            fr.z = hi ? u2b : u2a;
            fr.w = hi ? u3b : u3a;
            bf16x8 pb = __builtin_bit_cast(bf16x8, fr);
#pragma unroll
            for (int mt = 0; mt < 4; mt++)
                o[mt] = __builtin_amdgcn_mfma_f32_16x16x32_bf16(vaf[mt], pb, o[mt], 0, 0, 0);
        }
        cur ^= 1;
    }

    // ---- normalize + store ctx ----
    float inv = 1.0f / l_run;
    int q = b * 128 + qh * 64 + wave * 16 + l16;
#pragma unroll
    for (int mt = 0; mt < 4; mt++) {
        ushort4 pko;
        pko.x = f2bf(o[mt][0] * inv);
        pko.y = f2bf(o[mt][1] * inv);
        pko.z = f2bf(o[mt][2] * inv);
        pko.w = f2bf(o[mt][3] * inv);
        *(ushort4*)(Og + (size_t)q * 1024 + hoff + mt * 16 + quad * 4) = pko;
    }
}

// ---------------------------------------------------------------------------
extern "C" void kernel_launch(void* const* d_in, const int* in_sizes, int n_in,
                              void* d_out, int out_size, void* d_ws, size_t ws_size,
                              hipStream_t stream) {
    const float* x  = (const float*)d_in[0];
    const float* Wq = (const float*)d_in[1];
    const float* bq = (const float*)d_in[2];
    const float* Wk = (const float*)d_in[3];
    const float* bk = (const float*)d_in[4];
    const float* Wv = (const float*)d_in[5];
    const float* bv = (const float*)d_in[6];
    const float* Wo = (const float*)d_in[7];
    const float* bo = (const float*)d_in[8];
    float* out = (float*)d_out;

    uint8_t* ws = (uint8_t*)d_ws;
    uint16_t* x_bf  = (uint16_t*)(ws);                       // 8 MiB (dead after gemm0)
    uint16_t* wqkvt = (uint16_t*)(ws + (8u << 20));          // 6 MiB (dead after gemm0)
    uint16_t* wot   = (uint16_t*)(ws + (14u << 20));         // 2 MiB
    uint16_t* q_bf  = (uint16_t*)(ws + (16u << 20));         // 8 MiB
    uint16_t* k_bf  = (uint16_t*)(ws + (24u << 20));
    uint16_t* v_bf  = (uint16_t*)(ws + (32u << 20));
    uint16_t* ctx   = (uint16_t*)(ws + (40u << 20));         // 8 MiB
    // build products overlay the dead x_bf/wqkvt region:
    uint16_t* Vt_all = (uint16_t*)(ws);                      // 16*80*4096*2B = 10 MiB
    uint16_t* Kg2    = (uint16_t*)(ws + (11u << 20));        // 16*1024*64*2B =  2 MiB
    if (ws_size < (48u << 20)) return;

    cvt_x_kernel<<<4096, 256, 0, stream>>>(x, x_bf);
    tpose4<<<dim3(16, 16, 4), 256, 0, stream>>>(Wq, Wk, Wv, Wo, wqkvt, wot);
    gemm_bt<0><<<dim3(24, 32), 256, 0, stream>>>(x_bf, wqkvt, bq, bk, bv,
                                                 q_bf, nullptr);
    build_vt<<<dim3(80, 16), 256, 0, stream>>>(k_bf, v_bf, Vt_all, Kg2);
    attn_kernel<<<dim3(1024), 256, 0, stream>>>(q_bf, k_bf, Kg2, Vt_all, ctx);
    gemm_bt<1><<<dim3(8, 32), 256, 0, stream>>>(ctx, wot, bo, nullptr, nullptr,
                                                nullptr, out);
}

// Round 8
// 176.940 us; speedup vs baseline: 1.3577x; 1.0726x over previous
//
#include <hip/hip_runtime.h>
#include <stdint.h>

// ---------------------------------------------------------------------------
// SparseAttention: B=1 S=4096 D=1024 H=16 HD=64, BLOCK=128 C=32
// prep(cvt_x + W transpose) -> gemm_bt<0>(QKV, q pre-scaled 0.125*log2e) ->
// build_vt (gathered K copy + pre-transposed/swizzled V tiles) ->
// attn_kernel (v6 depth-1 pipeline: double-buffered DMA, ONE __syncthreads
// per chunk) -> gemm_bt<1> (128x64 tiles, 2 blocks/CU).
// Base-2 softmax. LDS XOR-swizzle: granule g of row r stored at g^(r&7).
// NOTE r7 ERRATA: relaxed s_waitcnt(vmcnt(4))+raw s_barrier pipeline broke
// correctness (absmax 1.55) -> reverted to full __syncthreads drain.
// ---------------------------------------------------------------------------

#define S_LEN 4096

typedef __bf16 bf16x8 __attribute__((ext_vector_type(8)));
typedef float  f32x4  __attribute__((ext_vector_type(4)));

__device__ __forceinline__ uint16_t f2bf(float f) {
    uint32_t u = __builtin_bit_cast(uint32_t, f);
    u += 0x7fffu + ((u >> 16) & 1u);   // RNE
    return (uint16_t)(u >> 16);
}
__device__ __forceinline__ uint32_t pack2bf(float lo, float hi) {
    return (uint32_t)f2bf(lo) | ((uint32_t)f2bf(hi) << 16);
}
__device__ __forceinline__ void gload_lds16(const uint16_t* g, uint16_t* l) {
    __builtin_amdgcn_global_load_lds(
        (const __attribute__((address_space(1))) void*)g,
        (__attribute__((address_space(3))) void*)l, 16, 0, 0);
}

// ---------------- prep: W [K][N] fp32 -> [N][K] bf16 (z<4)  +  x->bf16 -----
__global__ __launch_bounds__(256) void prep(const float* __restrict__ x,
                                            const float* __restrict__ Wq,
                                            const float* __restrict__ Wk,
                                            const float* __restrict__ Wv,
                                            const float* __restrict__ Wo,
                                            uint16_t* __restrict__ xb,
                                            uint16_t* __restrict__ wqkvt,
                                            uint16_t* __restrict__ wot) {
    const int z = blockIdx.z;
    if (z >= 4) {
        int id = (z - 4) * 256 + blockIdx.y * 16 + blockIdx.x;
        int i = (id * 256 + threadIdx.x) * 4;
        const float4 v = *(const float4*)(x + i);
        ushort4 o;
        o.x = f2bf(v.x); o.y = f2bf(v.y); o.z = f2bf(v.z); o.w = f2bf(v.w);
        *(ushort4*)(xb + i) = o;
        return;
    }
    __shared__ float tile[64][65];
    const float* src = (z == 0) ? Wq : (z == 1) ? Wk : (z == 2) ? Wv : Wo;
    uint16_t* dst = (z < 3) ? (wqkvt + (size_t)z * 1024 * 1024) : wot;
    const int ro = blockIdx.y * 64, co = blockIdx.x * 64;
    const int c = threadIdx.x & 63, r4 = threadIdx.x >> 6;
#pragma unroll
    for (int i = 0; i < 16; i++) {
        int r = i * 4 + r4;
        tile[r][c] = src[(size_t)(ro + r) * 1024 + co + c];
    }
    __syncthreads();
#pragma unroll
    for (int i = 0; i < 16; i++) {
        int cc = i * 4 + r4;
        dst[(size_t)(co + cc) * 1024 + ro + c] = f2bf(tile[c][cc]);
    }
}

// ---------------- GEMM: C[M][N] = A[M][1024] * Bt[N][1024]^T ---------------
// MODE 0: 128x128 tile, N=3072 qkv -> bf16 (operand-swapped C^T epilogue).
// MODE 1: 128x64 tile (512 blocks -> 2/CU), N=1024 -> fp32 + bias.
template <int MODE>
__global__ __launch_bounds__(256) void gemm_bt(const uint16_t* __restrict__ A,
                                               const uint16_t* __restrict__ Bt,
                                               const float* __restrict__ bias0,
                                               const float* __restrict__ bias1,
                                               const float* __restrict__ bias2,
                                               uint16_t* __restrict__ Cb,
                                               float* __restrict__ Cf) {
    constexpr int BN = (MODE == 0) ? 128 : 64;   // tile N
    constexpr int NT = (MODE == 0) ? 4 : 2;      // 16-wide n-tiles per wave
    __shared__ __attribute__((aligned(16))) uint16_t As[128 * 64];
    __shared__ __attribute__((aligned(16))) uint16_t Bs[BN * 64];
    const int tid = threadIdx.x;
    const int wave = tid >> 6, lane = tid & 63;
    const int quad = lane >> 4, l16 = lane & 15;
    const int row0 = blockIdx.y * 128, col0 = blockIdx.x * BN;
    const int wm = (wave >> 1) * 64, wn = (wave & 1) * (BN / 2);
    const int srow = lane >> 3, scol = lane & 7;
    const int gcol = (scol ^ srow) * 8;
    const int sw = (l16 & 7);

    f32x4 acc[4][NT];
    const f32x4 z4 = {0.f, 0.f, 0.f, 0.f};
#pragma unroll
    for (int i = 0; i < 4; i++)
#pragma unroll
        for (int j = 0; j < NT; j++) acc[i][j] = z4;

    for (int k0 = 0; k0 < 1024; k0 += 64) {
        __syncthreads();
#pragma unroll
        for (int i = 0; i < 4; i++) {
            int u = wave * 4 + i;
            int row = u * 8 + srow;
            gload_lds16(A + (size_t)(row0 + row) * 1024 + k0 + gcol, As + u * 512);
        }
#pragma unroll
        for (int i = 0; i < BN / 32; i++) {
            int u = wave * (BN / 32) + i;
            int row = u * 8 + srow;
            gload_lds16(Bt + (size_t)(col0 + row) * 1024 + k0 + gcol, Bs + u * 512);
        }
        __syncthreads();
#pragma unroll
        for (int kk = 0; kk < 2; kk++) {
            bf16x8 af[4], bfr[NT];
#pragma unroll
            for (int mt = 0; mt < 4; mt++)
                af[mt] = *(const bf16x8*)(As + (wm + mt * 16 + l16) * 64 + ((kk * 4 + quad) ^ sw) * 8);
#pragma unroll
            for (int nt = 0; nt < NT; nt++)
                bfr[nt] = *(const bf16x8*)(Bs + (wn + nt * 16 + l16) * 64 + ((kk * 4 + quad) ^ sw) * 8);
#pragma unroll
            for (int mt = 0; mt < 4; mt++)
#pragma unroll
                for (int nt = 0; nt < NT; nt++) {
                    if (MODE == 0)   // C^T orientation: reg index = n
                        acc[mt][nt] = __builtin_amdgcn_mfma_f32_16x16x32_bf16(
                            bfr[nt], af[mt], acc[mt][nt], 0, 0, 0);
                    else
                        acc[mt][nt] = __builtin_amdgcn_mfma_f32_16x16x32_bf16(
                            af[mt], bfr[nt], acc[mt][nt], 0, 0, 0);
                }
        }
    }

    if (MODE == 0) {
#pragma unroll
        for (int nt = 0; nt < NT; nt++) {
            int n = col0 + wn + nt * 16 + quad * 4;
            int which = n >> 10, c = n & 1023;
            const float* bp = (which == 0) ? bias0 : (which == 1 ? bias1 : bias2);
            const float4 b4 = *(const float4*)(bp + c);
            // q pre-scaled by 1/sqrt(64) * log2(e) for base-2 softmax
            float scv = (which == 0) ? 0.18033688f : 1.0f;
            uint16_t* op = Cb + (size_t)which * S_LEN * 1024 + c;
#pragma unroll
            for (int mt = 0; mt < 4; mt++) {
                int s = row0 + wm + mt * 16 + l16;
                ushort4 pkv;
                pkv.x = f2bf((acc[mt][nt][0] + b4.x) * scv);
                pkv.y = f2bf((acc[mt][nt][1] + b4.y) * scv);
                pkv.z = f2bf((acc[mt][nt][2] + b4.z) * scv);
                pkv.w = f2bf((acc[mt][nt][3] + b4.w) * scv);
                *(ushort4*)(op + (size_t)s * 1024) = pkv;
            }
        }
    } else {
#pragma unroll
        for (int nt = 0; nt < NT; nt++) {
            int n = col0 + wn + nt * 16 + l16;
            float bi = bias0[n];
#pragma unroll
            for (int mt = 0; mt < 4; mt++) {
                int row = row0 + wm + mt * 16 + quad * 4;
#pragma unroll
                for (int r = 0; r < 4; r++)
                    Cf[(size_t)(row + r) * 1024 + n] = acc[mt][nt][r] + bi;
            }
        }
    }
}

// ---------------- build gathered K + transposed V tiles --------------------
__global__ __launch_bounds__(256) void build_vt(const uint16_t* __restrict__ Kbf,
                                                const uint16_t* __restrict__ Vbf,
                                                uint16_t* __restrict__ Vt_all,
                                                uint16_t* __restrict__ Kg2) {
    __shared__ uint16_t T[64 * 66];
    const int c = blockIdx.x, h = blockIdx.y;
    const int tid = threadIdx.x;
#pragma unroll
    for (int i = 0; i < 2; i++) {
        int idx = i * 256 + tid;
        int kl = idx >> 3, c8 = idx & 7;
        int key;
        if (c < 64) key = c * 64 + kl;
        else { int t = (c - 64) * 64 + kl; int kb = t / 33, rr = t - kb * 33;
               key = kb * 128 + (rr == 0 ? 0 : 95 + rr); }
        uint4 v = *(const uint4*)(Vbf + (size_t)key * 1024 + h * 64 + c8 * 8);
        uint32_t* tp = (uint32_t*)(T + kl * 66 + c8 * 8);
        tp[0] = v.x; tp[1] = v.y; tp[2] = v.z; tp[3] = v.w;
        if (c >= 64) {
            int t = (c - 64) * 64 + kl;
            uint4 kv = *(const uint4*)(Kbf + (size_t)key * 1024 + h * 64 + c8 * 8);
            *(uint4*)(Kg2 + ((size_t)h * 1024 + t) * 64 + c8 * 8) = kv;
        }
    }
    __syncthreads();
#pragma unroll
    for (int i = 0; i < 2; i++) {
        int idx = i * 256 + tid;
        int hd = idx >> 3, kg8 = idx & 7;
        uint32_t w[4];
#pragma unroll
        for (int p = 0; p < 4; p++) {
            uint16_t lo = T[(kg8 * 8 + 2 * p) * 66 + hd];
            uint16_t hi = T[(kg8 * 8 + 2 * p + 1) * 66 + hd];
            w[p] = (uint32_t)lo | ((uint32_t)hi << 16);
        }
        uint4 o4 = {w[0], w[1], w[2], w[3]};
        *(uint4*)(Vt_all + ((size_t)(h * 80 + c) * 64 + hd) * 64 + ((kg8 ^ (hd & 7)) * 8)) = o4;
    }
}

// ---------------- sparse flash attention (v6 structure, proven) ------------
// 1024 jobs heavy-first: b=31-(job>>5), h=(job&31)>>1, qh=job&1 (64 q each).
// 256 thr = 4 waves x 16 q. All K/Vt staging is contiguous coalesced DMA
// (gather precomputed). ONE __syncthreads per chunk; K+Vt double-buffered.
__global__ __launch_bounds__(256, 4) void attn_kernel(const uint16_t* __restrict__ Qg,
                                                      const uint16_t* __restrict__ Kbf,
                                                      const uint16_t* __restrict__ Kg2,
                                                      const uint16_t* __restrict__ Vt_all,
                                                      uint16_t* __restrict__ Og) {
    __shared__ __attribute__((aligned(16))) uint16_t SM[16384];  // 32 KiB
    // Kbuf(cur)  = SM + cur*4096        (8 KiB each)
    // Vtbuf(cur) = SM + 8192 + cur*4096 (8 KiB each); Q staged at SM+8192 pre-loop

    const int job = blockIdx.x;
    const int b = 31 - (job >> 5);
    const int h = (job & 31) >> 1, qh = job & 1;
    const int nprev = 33 * b;
    const int ngc = (nprev + 63) >> 6;
    const int ntot = ngc + 1 + qh;          // qh=0 skips own chunk 1 (fully masked)
    const size_t hoff = (size_t)h * 64;

    const int tid = threadIdx.x;
    const int wave = tid >> 6, lane = tid & 63;
    const int quad = lane >> 4, l16 = lane & 15;
    const int sw = l16 & 7;

    // ---- stage Q half-tile [64][64] into SM+8192, hoist frags to regs
#pragma unroll
    for (int i = 0; i < 2; i++) {
        int idx = i * 256 + tid;
        int row = idx >> 3, c8 = idx & 7;
        gload_lds16(Qg + (size_t)(b * 128 + qh * 64 + row) * 1024 + hoff + ((c8 ^ (row & 7)) * 8),
                    SM + 8192 + idx * 8);
    }
    __syncthreads();
    bf16x8 qb[2];
#pragma unroll
    for (int kk = 0; kk < 2; kk++)
        qb[kk] = *(const bf16x8*)(SM + 8192 + (wave * 16 + l16) * 64 + (((kk * 4 + quad) ^ sw) * 8));
    __syncthreads();   // everyone has Q frags before DMA overwrites the region

    // ---- DMA chunk ci into buf
    auto stage = [&](int ci, int buf) {
        int vchunk = (ci < ngc) ? (64 + ci) : (2 * b + (ci - ngc));
        const uint16_t* vsrc = Vt_all + ((size_t)(h * 80 + vchunk) * 64) * 64;
#pragma unroll
        for (int i = 0; i < 2; i++) {
            int idx = i * 256 + tid;
            int row = idx >> 3, c8 = idx & 7;
            const uint16_t* kp;
            if (ci < ngc)
                kp = Kg2 + ((size_t)h * 1024 + ci * 64 + row) * 64 + ((c8 ^ (row & 7)) * 8);
            else
                kp = Kbf + (size_t)(b * 128 + (ci - ngc) * 64 + row) * 1024 + hoff + ((c8 ^ (row & 7)) * 8);
            gload_lds16(kp, SM + buf * 4096 + idx * 8);
            gload_lds16(vsrc + idx * 8, SM + 8192 + buf * 4096 + idx * 8);
        }
    };
    stage(0, 0);

    float m_run = -3e38f, l_run = 0.f;
    f32x4 o[4];
    const f32x4 z4 = {0.f, 0.f, 0.f, 0.f};
#pragma unroll
    for (int mt = 0; mt < 4; mt++) o[mt] = z4;

    const int ql = qh * 64 + wave * 16 + l16;   // local q for masking
    const int srcA = l16 + 32 * (quad & 1);
    const bool hi = (quad >> 1) != 0;

    int cur = 0;
    for (int ci = 0; ci < ntot; ci++) {
        __syncthreads();   // drains own DMA(ci) (full prior-iter slack); all
                           // waves done reading buf(ci-1) before we overwrite it
        if (ci + 1 < ntot) stage(ci + 1, cur ^ 1);

        const uint16_t* Kc = SM + cur * 4096;
        const uint16_t* Vc = SM + 8192 + cur * 4096;

        // S^T = K.Q^T  (C: col=q=l16, row=key)
        f32x4 s[4];
#pragma unroll
        for (int kt = 0; kt < 4; kt++) s[kt] = z4;
#pragma unroll
        for (int kk = 0; kk < 2; kk++) {
            bf16x8 ka[4];
#pragma unroll
            for (int kt = 0; kt < 4; kt++)
                ka[kt] = *(const bf16x8*)(Kc + (kt * 16 + l16) * 64 + (((kk * 4 + quad) ^ sw) * 8));
#pragma unroll
            for (int kt = 0; kt < 4; kt++)
                s[kt] = __builtin_amdgcn_mfma_f32_16x16x32_bf16(ka[kt], qb[kk], s[kt], 0, 0, 0);
        }

        // masking
        if (ci >= ngc) {
            int cb = ci - ngc;
#pragma unroll
            for (int kt = 0; kt < 4; kt++) {
                int keyl = cb * 64 + kt * 16 + quad * 4;
#pragma unroll
                for (int r = 0; r < 4; r++)
                    if (keyl + r > ql) s[kt][r] = -1e30f;
            }
        } else if (ci == ngc - 1) {
#pragma unroll
            for (int kt = 0; kt < 4; kt++) {
                int tg = ci * 64 + kt * 16 + quad * 4;
#pragma unroll
                for (int r = 0; r < 4; r++)
                    if (tg + r >= nprev) s[kt][r] = -1e30f;
            }
        }

        // online softmax (base 2) + pack P
        uint32_t pk[4][2];
        float al;
        {
            float mx = -3e38f;
#pragma unroll
            for (int kt = 0; kt < 4; kt++)
#pragma unroll
                for (int r = 0; r < 4; r++) mx = fmaxf(mx, s[kt][r]);
            mx = fmaxf(mx, __shfl_xor(mx, 16));
            mx = fmaxf(mx, __shfl_xor(mx, 32));
            float mn = fmaxf(m_run, mx);
            float sub = fmaxf(mn, -1e20f);
            al = exp2f(m_run - sub);
            m_run = mn;
            float ps = 0.f;
#pragma unroll
            for (int kt = 0; kt < 4; kt++) {
                float p0 = exp2f(s[kt][0] - sub);
                float p1 = exp2f(s[kt][1] - sub);
                float p2 = exp2f(s[kt][2] - sub);
                float p3 = exp2f(s[kt][3] - sub);
                ps += (p0 + p1) + (p2 + p3);
                pk[kt][0] = pack2bf(p0, p1);
                pk[kt][1] = pack2bf(p2, p3);
            }
            ps += __shfl_xor(ps, 16);
            ps += __shfl_xor(ps, 32);
            l_run = l_run * al + ps;
        }
#pragma unroll
        for (int mt = 0; mt < 4; mt++)
#pragma unroll
            for (int r = 0; r < 4; r++) o[mt][r] *= al;

        // O^T += V^T . P^T  (Vt pre-transposed in LDS; P frag via shuffles)
#pragma unroll
        for (int kk = 0; kk < 2; kk++) {
            bf16x8 vaf[4];
#pragma unroll
            for (int mt = 0; mt < 4; mt++)
                vaf[mt] = *(const bf16x8*)(Vc + (mt * 16 + l16) * 64 + (((kk * 4 + quad) ^ sw) * 8));
            uint32_t u0a = (uint32_t)__shfl((int)pk[2 * kk][0], srcA);
            uint32_t u0b = (uint32_t)__shfl((int)pk[2 * kk + 1][0], srcA);
            uint32_t u1a = (uint32_t)__shfl((int)pk[2 * kk][1], srcA);
            uint32_t u1b = (uint32_t)__shfl((int)pk[2 * kk + 1][1], srcA);
            uint32_t u2a = (uint32_t)__shfl((int)pk[2 * kk][0], srcA + 16);
            uint32_t u2b = (uint32_t)__shfl((int)pk[2 * kk + 1][0], srcA + 16);
            uint32_t u3a = (uint32_t)__shfl((int)pk[2 * kk][1], srcA + 16);
            uint32_t u3b = (uint32_t)__shfl((int)pk[2 * kk + 1][1], srcA + 16);
            uint4 fr;
            fr.x = hi ? u0b : u0a;
            fr.y = hi ? u1b : u1a;
            fr.z = hi ? u2b : u2a;
            fr.w = hi ? u3b : u3a;
            bf16x8 pb = __builtin_bit_cast(bf16x8, fr);
#pragma unroll
            for (int mt = 0; mt < 4; mt++)
                o[mt] = __builtin_amdgcn_mfma_f32_16x16x32_bf16(vaf[mt], pb, o[mt], 0, 0, 0);
        }
        cur ^= 1;
    }

    // ---- normalize + store ctx ----
    float inv = 1.0f / l_run;
    int q = b * 128 + qh * 64 + wave * 16 + l16;
#pragma unroll
    for (int mt = 0; mt < 4; mt++) {
        ushort4 pko;
        pko.x = f2bf(o[mt][0] * inv);
        pko.y = f2bf(o[mt][1] * inv);
        pko.z = f2bf(o[mt][2] * inv);
        pko.w = f2bf(o[mt][3] * inv);
        *(ushort4*)(Og + (size_t)q * 1024 + hoff + mt * 16 + quad * 4) = pko;
    }
}

// ---------------------------------------------------------------------------
extern "C" void kernel_launch(void* const* d_in, const int* in_sizes, int n_in,
                              void* d_out, int out_size, void* d_ws, size_t ws_size,
                              hipStream_t stream) {
    const float* x  = (const float*)d_in[0];
    const float* Wq = (const float*)d_in[1];
    const float* bq = (const float*)d_in[2];
    const float* Wk = (const float*)d_in[3];
    const float* bk = (const float*)d_in[4];
    const float* Wv = (const float*)d_in[5];
    const float* bv = (const float*)d_in[6];
    const float* Wo = (const float*)d_in[7];
    const float* bo = (const float*)d_in[8];
    float* out = (float*)d_out;

    uint8_t* ws = (uint8_t*)d_ws;
    uint16_t* x_bf  = (uint16_t*)(ws);                       // 8 MiB (dead after gemm0)
    uint16_t* wqkvt = (uint16_t*)(ws + (8u << 20));          // 6 MiB (dead after gemm0)
    uint16_t* wot   = (uint16_t*)(ws + (14u << 20));         // 2 MiB
    uint16_t* q_bf  = (uint16_t*)(ws + (16u << 20));         // 8 MiB
    uint16_t* k_bf  = (uint16_t*)(ws + (24u << 20));
    uint16_t* v_bf  = (uint16_t*)(ws + (32u << 20));
    uint16_t* ctx   = (uint16_t*)(ws + (40u << 20));         // 8 MiB
    // build products overlay the dead x_bf/wqkvt region:
    uint16_t* Vt_all = (uint16_t*)(ws);                      // 16*80*4096*2B = 10 MiB
    uint16_t* Kg2    = (uint16_t*)(ws + (11u << 20));        // 16*1024*64*2B =  2 MiB
    if (ws_size < (48u << 20)) return;

    prep<<<dim3(16, 16, 20), 256, 0, stream>>>(x, Wq, Wk, Wv, Wo, x_bf, wqkvt, wot);
    gemm_bt<0><<<dim3(24, 32), 256, 0, stream>>>(x_bf, wqkvt, bq, bk, bv,
                                                 q_bf, nullptr);
    build_vt<<<dim3(80, 16), 256, 0, stream>>>(k_bf, v_bf, Vt_all, Kg2);
    attn_kernel<<<dim3(1024), 256, 0, stream>>>(q_bf, k_bf, Kg2, Vt_all, ctx);
    gemm_bt<1><<<dim3(16, 32), 256, 0, stream>>>(ctx, wot, bo, nullptr, nullptr,
                                                 nullptr, out);
}